// Round 12
// baseline (45.722 us; speedup 1.0000x reference)
//
#include <hip/hip_runtime.h>

// out[f, t, lm, k] (F=512, T=1024, LM=12, K=8) fp32:
//   l = lm/4, m = lm%4, s = k+l ; t < s -> 0
//   fs = (f - s) & 511 ; o = fs*24 + k*3 + l
//   val = b[o] + sum_{tap} w[o*3+tap] * x[m, t-2+tap, fs]   (neg time taps = 0)
//
// Block = (16 features x 32 t), 384 threads (fl = tid/24, u = tid%24),
// 1024 blocks — all resident. vs round 11 (FB=8): staged-read line traffic
// ~37 MB -> ~23 MB, and half the blocks (one-shot staging cost halves).
// Stores are NON-TEMPORAL: 201 MB write-once stream bypasses L2/L3 allocation
// so the x slab stays cache-resident for the staging reads (read/write
// contention was the residual theory after round 11).
// Slab: x_lds[m][tt][fi], fi=0..24 <-> feature (f0-9+fi)&511, tt=0..33 <-> t0-2+tt.
// XROW=25 (odd -> bank spread). Per-thread fixed fi window, sliding 3-row
// register window over t: per iter 1 row load (4 dwords LDS), 12 FMA,
// 1 f32x4 nt-store (24-lane 384 B contiguous runs; every touched line
// fully written by one instruction).

typedef float f32x4 __attribute__((ext_vector_type(4)));

#define NF 512
#define NT 1024
#define FB 16
#define TT 32
#define XROW 25
#define NROWS (TT + 2)        // 34
#define XM (NROWS * XROW)     // 850
#define SLAB (4 * XM)         // 3400

__global__ __launch_bounds__(384, 4) void caconv_kernel(
    const float* __restrict__ x,   // [4][1024][512]
    const float* __restrict__ w,   // [12288*3]
    const float* __restrict__ b,   // [12288]
    float* __restrict__ out)       // [512][1024][12][8]
{
    __shared__ float x_lds[SLAB];      // 13.6 KB
    __shared__ float w_lds[FB * 72];   // [fl][l][tap][k]
    __shared__ float b_lds[FB * 24];   // [fl][l][k]

    const int tid = threadIdx.x;
    const int f0  = (blockIdx.x >> 5) * FB;
    const int t0  = (blockIdx.x & 31) * TT;

    // ---- stage w ([fl][l][tap][k]) and b ([fl][l][k]): 1536 floats ----
    for (int i = tid; i < FB * 96; i += 384) {
        if (i < FB * 72) {
            const int fl = i / 72, r = i - fl * 72;
            const int l = r / 24, r2 = r - l * 24, tap = r2 >> 3, k = r2 & 7;
            const int fs = (f0 + fl - k - l + NF) & (NF - 1);
            w_lds[i] = w[(fs * 24 + k * 3 + l) * 3 + tap];
        } else {
            const int j = i - FB * 72;
            const int fl = j / 24, r = j - fl * 24, l = r >> 3, k = r & 7;
            const int fs = (f0 + fl - k - l + NF) & (NF - 1);
            b_lds[j] = b[fs * 24 + k * 3 + l];
        }
    }

    // ---- stage x slab: 4m x 34 rows x 25 fi = 3400 floats ----
    for (int i = tid; i < SLAB; i += 384) {
        const int fi  = i % XROW;
        const int row = i / XROW;
        const int tt  = row % NROWS;
        const int m   = row / NROWS;
        const int tg  = t0 - 2 + tt;
        const int fs  = (f0 - 9 + fi + NF) & (NF - 1);
        float v = 0.0f;
        if (tg >= 0) v = x[((m << 10) + tg) * NF + fs];
        x_lds[m * XM + tt * XROW + fi] = v;
    }
    __syncthreads();

    // ---- thread decode: fl (feature), lm, k-half ----
    const int fl = tid / 24;
    const int u  = tid - fl * 24;
    const int lm = u >> 1;
    const int k0 = (u & 1) << 2;
    const int l  = lm >> 2;
    const int m  = lm & 3;
    const int fib = fl + 6 - l - k0;     // fi of kk=3; fi(kk) = fib + 3 - kk

    const float* wp = w_lds + fl * 72 + l * 24 + k0;
    const f32x4 w0 = *(const f32x4*)(wp);
    const f32x4 w1 = *(const f32x4*)(wp + 8);
    const f32x4 w2 = *(const f32x4*)(wp + 16);
    const f32x4 bias = *(const f32x4*)(b_lds + fl * 24 + l * 8 + k0);

    const float* xp = x_lds + m * XM + fib;
    float* outp = out + ((size_t)(f0 + fl) * NT + t0) * 96 + lm * 8 + k0;

    // sliding 3-row window: rA=row(t_off), rB=row(t_off+1), rC=row(t_off+2)
    f32x4 rA, rB, rC;
    rA[0] = xp[0];  rA[1] = xp[1];  rA[2] = xp[2];  rA[3] = xp[3];
    rB[0] = xp[XROW]; rB[1] = xp[XROW+1]; rB[2] = xp[XROW+2]; rB[3] = xp[XROW+3];

#pragma unroll 4
    for (int t_off = 0; t_off < TT; ++t_off) {
        const float* rp = xp + (t_off + 2) * XROW;
        rC[0] = rp[0]; rC[1] = rp[1]; rC[2] = rp[2]; rC[3] = rp[3];

        f32x4 acc = bias;
        acc[0] += w0[0] * rA[3]; acc[1] += w0[1] * rA[2];
        acc[2] += w0[2] * rA[1]; acc[3] += w0[3] * rA[0];
        acc[0] += w1[0] * rB[3]; acc[1] += w1[1] * rB[2];
        acc[2] += w1[2] * rB[1]; acc[3] += w1[3] * rB[0];
        acc[0] += w2[0] * rC[3]; acc[1] += w2[1] * rC[2];
        acc[2] += w2[2] * rC[1]; acc[3] += w2[3] * rC[0];

        if (t0 == 0 && t_off < 10) {   // zero guard: t < k + l
#pragma unroll
            for (int kk = 0; kk < 4; ++kk)
                if (t_off < k0 + kk + l) acc[kk] = 0.0f;
        }

        __builtin_nontemporal_store(acc, (f32x4*)outp);
        outp += 96;

        rA = rB; rB = rC;
    }
}

extern "C" void kernel_launch(void* const* d_in, const int* in_sizes, int n_in,
                              void* d_out, int out_size, void* d_ws, size_t ws_size,
                              hipStream_t stream)
{
    const float* x = (const float*)d_in[0];
    const float* w = (const float*)d_in[1];
    const float* b = (const float*)d_in[2];
    float* out = (float*)d_out;

    const int grid = (NF / FB) * (NT / TT);   // 32 * 32 = 1024 blocks
    caconv_kernel<<<grid, 384, 0, stream>>>(x, w, b, out);
}

// Round 13
// 39.625 us; speedup vs baseline: 1.1539x; 1.1539x over previous
//
#include <hip/hip_runtime.h>

// out[f, t, lm, k] (F=512, T=1024, LM=12, K=8) fp32:
//   l = lm/4, m = lm%4, s = k+l ; t < s -> 0
//   fs = (f - s) & 511 ; o = fs*24 + k*3 + l
//   val = b[o] + sum_{tap} w[o*3+tap] * x[m, t-2+tap, fs]   (neg time taps = 0)
//
// Block = (16 features x 32 t), 384 threads (fl = tid/24, u = tid%24),
// 1024 blocks — all resident. Staged-read line traffic ~23 MB (vs 37 MB at
// FB=8). A/B vs round 12: ONLY change is plain stores instead of
// __builtin_nontemporal_store (isolating the nt-store regression).
// Slab: x_lds[m][tt][fi], fi=0..24 <-> feature (f0-9+fi)&511, tt=0..33 <-> t0-2+tt.
// XROW=25 (odd -> bank spread). Per-thread fixed fi window, sliding 3-row
// register window over t: per iter 1 row load (4 dwords LDS), 12 FMA,
// 1 f32x4 store (24-lane 384 B contiguous runs; every touched 64 B line
// fully written by one instruction).

typedef float f32x4 __attribute__((ext_vector_type(4)));

#define NF 512
#define NT 1024
#define FB 16
#define TT 32
#define XROW 25
#define NROWS (TT + 2)        // 34
#define XM (NROWS * XROW)     // 850
#define SLAB (4 * XM)         // 3400

__global__ __launch_bounds__(384, 4) void caconv_kernel(
    const float* __restrict__ x,   // [4][1024][512]
    const float* __restrict__ w,   // [12288*3]
    const float* __restrict__ b,   // [12288]
    float* __restrict__ out)       // [512][1024][12][8]
{
    __shared__ float x_lds[SLAB];      // 13.6 KB
    __shared__ float w_lds[FB * 72];   // [fl][l][tap][k]
    __shared__ float b_lds[FB * 24];   // [fl][l][k]

    const int tid = threadIdx.x;
    const int f0  = (blockIdx.x >> 5) * FB;
    const int t0  = (blockIdx.x & 31) * TT;

    // ---- stage w ([fl][l][tap][k]) and b ([fl][l][k]): 1536 floats ----
    for (int i = tid; i < FB * 96; i += 384) {
        if (i < FB * 72) {
            const int fl = i / 72, r = i - fl * 72;
            const int l = r / 24, r2 = r - l * 24, tap = r2 >> 3, k = r2 & 7;
            const int fs = (f0 + fl - k - l + NF) & (NF - 1);
            w_lds[i] = w[(fs * 24 + k * 3 + l) * 3 + tap];
        } else {
            const int j = i - FB * 72;
            const int fl = j / 24, r = j - fl * 24, l = r >> 3, k = r & 7;
            const int fs = (f0 + fl - k - l + NF) & (NF - 1);
            b_lds[j] = b[fs * 24 + k * 3 + l];
        }
    }

    // ---- stage x slab: 4m x 34 rows x 25 fi = 3400 floats ----
    for (int i = tid; i < SLAB; i += 384) {
        const int fi  = i % XROW;
        const int row = i / XROW;
        const int tt  = row % NROWS;
        const int m   = row / NROWS;
        const int tg  = t0 - 2 + tt;
        const int fs  = (f0 - 9 + fi + NF) & (NF - 1);
        float v = 0.0f;
        if (tg >= 0) v = x[((m << 10) + tg) * NF + fs];
        x_lds[m * XM + tt * XROW + fi] = v;
    }
    __syncthreads();

    // ---- thread decode: fl (feature), lm, k-half ----
    const int fl = tid / 24;
    const int u  = tid - fl * 24;
    const int lm = u >> 1;
    const int k0 = (u & 1) << 2;
    const int l  = lm >> 2;
    const int m  = lm & 3;
    const int fib = fl + 6 - l - k0;     // fi of kk=3; fi(kk) = fib + 3 - kk

    const float* wp = w_lds + fl * 72 + l * 24 + k0;
    const f32x4 w0 = *(const f32x4*)(wp);
    const f32x4 w1 = *(const f32x4*)(wp + 8);
    const f32x4 w2 = *(const f32x4*)(wp + 16);
    const f32x4 bias = *(const f32x4*)(b_lds + fl * 24 + l * 8 + k0);

    const float* xp = x_lds + m * XM + fib;
    float* outp = out + ((size_t)(f0 + fl) * NT + t0) * 96 + lm * 8 + k0;

    // sliding 3-row window: rA=row(t_off), rB=row(t_off+1), rC=row(t_off+2)
    f32x4 rA, rB, rC;
    rA[0] = xp[0];  rA[1] = xp[1];  rA[2] = xp[2];  rA[3] = xp[3];
    rB[0] = xp[XROW]; rB[1] = xp[XROW+1]; rB[2] = xp[XROW+2]; rB[3] = xp[XROW+3];

#pragma unroll 4
    for (int t_off = 0; t_off < TT; ++t_off) {
        const float* rp = xp + (t_off + 2) * XROW;
        rC[0] = rp[0]; rC[1] = rp[1]; rC[2] = rp[2]; rC[3] = rp[3];

        f32x4 acc = bias;
        acc[0] += w0[0] * rA[3]; acc[1] += w0[1] * rA[2];
        acc[2] += w0[2] * rA[1]; acc[3] += w0[3] * rA[0];
        acc[0] += w1[0] * rB[3]; acc[1] += w1[1] * rB[2];
        acc[2] += w1[2] * rB[1]; acc[3] += w1[3] * rB[0];
        acc[0] += w2[0] * rC[3]; acc[1] += w2[1] * rC[2];
        acc[2] += w2[2] * rC[1]; acc[3] += w2[3] * rC[0];

        if (t0 == 0 && t_off < 10) {   // zero guard: t < k + l
#pragma unroll
            for (int kk = 0; kk < 4; ++kk)
                if (t_off < k0 + kk + l) acc[kk] = 0.0f;
        }

        *(f32x4*)outp = acc;
        outp += 96;

        rA = rB; rB = rC;
    }
}

extern "C" void kernel_launch(void* const* d_in, const int* in_sizes, int n_in,
                              void* d_out, int out_size, void* d_ws, size_t ws_size,
                              hipStream_t stream)
{
    const float* x = (const float*)d_in[0];
    const float* w = (const float*)d_in[1];
    const float* b = (const float*)d_in[2];
    float* out = (float*)d_out;

    const int grid = (NF / FB) * (NT / TT);   // 32 * 32 = 1024 blocks
    caconv_kernel<<<grid, 384, 0, stream>>>(x, w, b, out);
}

// Round 15
// 38.573 us; speedup vs baseline: 1.1853x; 1.0273x over previous
//
#include <hip/hip_runtime.h>

// out[f, t, lm, k] (F=512, T=1024, LM=12, K=8) fp32:
//   l = lm/4, m = lm%4, s = k+l ; t < s -> 0
//   fs = (f - s) & 511 ; o = fs*24 + k*3 + l
//   val = b[o] + sum_{tap} w[o*3+tap] * x[m, t-2+tap, fs]   (neg time taps = 0)
//
// Persistent block = (16 features x 64 t) as TWO 32-t tiles, 384 threads,
// 512 blocks (all resident). Double-buffered slab: prologue stages tile 0;
// tile 1's global loads issue to regs BEFORE tile-0 compute, ds_write + one
// barrier after. Compute/store identical to round 13 (39.6 us).
// Slab: x_lds[m][tt][fi], fi=0..24 <-> (f0-9+fi)&511, tt=0..33 <-> t0-2+tt;
// XROW=25, XM=850, SLAB=3400 used; SLABA=3408 allocated -> DUMMY=3400 is a
// true pad slot (round-14 bug: DUMMY=SLAB-1 aliased real slot (3,33,24)).

typedef float f32x4 __attribute__((ext_vector_type(4)));

#define NF 512
#define NT 1024
#define FB 16
#define TT 32
#define XROW 25
#define NROWS (TT + 2)        // 34
#define XM (NROWS * XROW)     // 850
#define SLAB (4 * XM)         // 3400 used dwords
#define SLABA (SLAB + 8)      // allocated stride (pad for DUMMY)
#define NIT 9                 // ceil(3400/384)
#define DUMMY SLAB            // pad slot, never read

__global__ __launch_bounds__(384, 3) void caconv_kernel(
    const float* __restrict__ x,   // [4][1024][512]
    const float* __restrict__ w,   // [12288*3]
    const float* __restrict__ b,   // [12288]
    float* __restrict__ out)       // [512][1024][12][8]
{
    __shared__ float x_lds[2 * SLABA];  // 27.3 KB
    __shared__ float w_lds[FB * 72];    // [fl][l][tap][k]
    __shared__ float b_lds[FB * 24];    // [fl][l][k]

    const int tid   = threadIdx.x;
    const int f0    = (blockIdx.x >> 4) * FB;
    const int tbase = (blockIdx.x & 15) * (2 * TT);

    // ---- stage w ([fl][l][tap][k]) and b ([fl][l][k]): 1536 floats ----
    for (int i = tid; i < FB * 96; i += 384) {
        if (i < FB * 72) {
            const int fl = i / 72, r = i - fl * 72;
            const int l = r / 24, r2 = r - l * 24, tap = r2 >> 3, k = r2 & 7;
            const int fs = (f0 + fl - k - l + NF) & (NF - 1);
            w_lds[i] = w[(fs * 24 + k * 3 + l) * 3 + tap];
        } else {
            const int j = i - FB * 72;
            const int fl = j / 24, r = j - fl * 24, l = r >> 3, k = r & 7;
            const int fs = (f0 + fl - k - l + NF) & (NF - 1);
            b_lds[j] = b[fs * 24 + k * 3 + l];
        }
    }

    // ---- precompute staging offsets (tile-invariant) ----
    int goff[NIT], pk[NIT];
#pragma unroll
    for (int it = 0; it < NIT; ++it) {
        const int i = tid + it * 384;
        if (i < SLAB) {
            const int fi  = i % XROW;
            const int row = i / XROW;
            const int tt  = row % NROWS;
            const int m   = row / NROWS;
            const int fs  = (f0 - 9 + fi + NF) & (NF - 1);
            goff[it] = ((tt - 2) << 9) + fs;          // + t0*512 at use
            pk[it]   = ((m * XM + tt * XROW + fi) << 2) | m;
        } else {
            goff[it] = -(1 << 30);                    // guard -> v=0 -> DUMMY
            pk[it]   = DUMMY << 2;
        }
    }

    float r[NIT];

    // ---- prologue: stage tile 0 into buffer 0 ----
#pragma unroll
    for (int it = 0; it < NIT; ++it) {
        const int g = goff[it] + (tbase << 9);
        float v = 0.0f;
        if (g >= 0) v = x[g + ((pk[it] & 3) << 19)];
        r[it] = v;
    }
#pragma unroll
    for (int it = 0; it < NIT; ++it) x_lds[pk[it] >> 2] = r[it];
    __syncthreads();

    // ---- thread decode (tile-invariant) ----
    const int fl = tid / 24;
    const int u  = tid - fl * 24;
    const int lm = u >> 1;
    const int k0 = (u & 1) << 2;
    const int l  = lm >> 2;
    const int m  = lm & 3;
    const int fib = fl + 6 - l - k0;     // fi of kk=3; fi(kk) = fib + 3 - kk

    const float* wp = w_lds + fl * 72 + l * 24 + k0;
    const f32x4 w0 = *(const f32x4*)(wp);
    const f32x4 w1 = *(const f32x4*)(wp + 8);
    const f32x4 w2 = *(const f32x4*)(wp + 16);
    const f32x4 bias = *(const f32x4*)(b_lds + fl * 24 + l * 8 + k0);

#pragma unroll 1
    for (int j = 0; j < 2; ++j) {
        const int t0 = tbase + j * TT;

        // issue tile-1 loads early: they ride under tile-0 compute+stores
        if (j == 0) {
            const int t1s = (tbase + TT) << 9;
#pragma unroll
            for (int it = 0; it < NIT; ++it) {
                const int g = goff[it] + t1s;          // >= 0 except guards
                float v = 0.0f;
                if (g >= 0) v = x[g + ((pk[it] & 3) << 19)];
                r[it] = v;
            }
        }

        const float* xp = x_lds + j * SLABA + m * XM + fib;
        float* outp = out + ((size_t)(f0 + fl) * NT + t0) * 96 + lm * 8 + k0;

        f32x4 rA, rB, rC;
        rA[0] = xp[0];  rA[1] = xp[1];  rA[2] = xp[2];  rA[3] = xp[3];
        rB[0] = xp[XROW]; rB[1] = xp[XROW+1]; rB[2] = xp[XROW+2]; rB[3] = xp[XROW+3];

#pragma unroll 4
        for (int t_off = 0; t_off < TT; ++t_off) {
            const float* rp = xp + (t_off + 2) * XROW;
            rC[0] = rp[0]; rC[1] = rp[1]; rC[2] = rp[2]; rC[3] = rp[3];

            f32x4 acc = bias;
            acc[0] += w0[0] * rA[3]; acc[1] += w0[1] * rA[2];
            acc[2] += w0[2] * rA[1]; acc[3] += w0[3] * rA[0];
            acc[0] += w1[0] * rB[3]; acc[1] += w1[1] * rB[2];
            acc[2] += w1[2] * rB[1]; acc[3] += w1[3] * rB[0];
            acc[0] += w2[0] * rC[3]; acc[1] += w2[1] * rC[2];
            acc[2] += w2[2] * rC[1]; acc[3] += w2[3] * rC[0];

            if (t0 == 0 && t_off < 10) {   // zero guard: t < k + l
#pragma unroll
                for (int kk = 0; kk < 4; ++kk)
                    if (t_off < k0 + kk + l) acc[kk] = 0.0f;
            }

            *(f32x4*)outp = acc;
            outp += 96;

            rA = rB; rB = rC;
        }

        // ---- write tile 1 into buffer 1, single barrier ----
        if (j == 0) {
#pragma unroll
            for (int it = 0; it < NIT; ++it) x_lds[SLABA + (pk[it] >> 2)] = r[it];
            __syncthreads();
        }
    }
}

extern "C" void kernel_launch(void* const* d_in, const int* in_sizes, int n_in,
                              void* d_out, int out_size, void* d_ws, size_t ws_size,
                              hipStream_t stream)
{
    const float* x = (const float*)d_in[0];
    const float* w = (const float*)d_in[1];
    const float* b = (const float*)d_in[2];
    float* out = (float*)d_out;

    const int grid = (NF / FB) * (NT / (2 * TT));   // 32 * 16 = 512 blocks
    caconv_kernel<<<grid, 384, 0, stream>>>(x, w, b, out);
}